// Round 6
// baseline (177.980 us; speedup 1.0000x reference)
//
#include <hip/hip_runtime.h>
#include <hip/hip_bf16.h>

#define BATCH 16
#define CH    256
#define HW    1024
#define NH    4
#define DH    64
#define NG    32
#define CPG   8
#define EPSV  1e-6f

// log2(e) / sqrt(C) folded into Q so softmax = exp2(S_scaled)
#define QSCALE 0.090168440055558706f

typedef __bf16 bf16x8 __attribute__((ext_vector_type(8)));
typedef float  f32x4  __attribute__((ext_vector_type(4)));

__device__ __forceinline__ unsigned short f2bf(float f) {
    union { __hip_bfloat16 h; unsigned short u; } cv;
    cv.h = __float2bfloat16(f);
    return cv.u;
}

__device__ __forceinline__ unsigned int fbits(float f) {
    union { float f; unsigned int u; } cv; cv.f = f; return cv.u;
}

__device__ __forceinline__ float bfu(unsigned int u) {
    union { unsigned int u; float f; } cv; cv.u = u; return cv.f;
}

__device__ __forceinline__ void gld_lds16(const unsigned short* g, unsigned short* l) {
    __builtin_amdgcn_global_load_lds(
        (const __attribute__((address_space(1))) void*)g,
        (__attribute__((address_space(3))) void*)l, 16, 0, 0);
}

// ---------------- merged: GN stats (blocks 0..511) + weight prep (blocks 512+) ----
__global__ void prep_stats_kernel(const float* x, const float* scale, const float* bias,
                                  const float* Wq, const float* Wk, const float* Wv,
                                  const float* Wp, const float* bq, const float* bk,
                                  const float* bv, float* coefA, float* coefB,
                                  unsigned short* wqkv_t, unsigned short* wp_t,
                                  float* bqkv) {
    int t = threadIdx.x;
    if (blockIdx.x >= 512) {
        int idx = (blockIdx.x - 512) * 256 + t;
        if (idx < 768 * 256) {
            int n = idx >> 8, c = idx & 255;
            const float* W = (n < 256) ? Wq : (n < 512) ? Wk : Wv;
            int d = n & 255;
            wqkv_t[idx] = f2bf(W[c * 256 + d]);
        } else if (idx < 768 * 256 + 256 * 256) {
            int j = idx - 768 * 256;
            int n = j >> 8, c = j & 255;
            wp_t[j] = f2bf(Wp[c * 256 + n]);
        }
        if (idx < 768)
            bqkv[idx] = (idx < 256) ? bq[idx] : (idx < 512) ? bk[idx - 256] : bv[idx - 512];
        return;
    }
    int bg = blockIdx.x;                       // b*32+g, group data contiguous
    const float4* p = reinterpret_cast<const float4*>(x + (size_t)bg * (CPG * HW));
    float s = 0.f, ss = 0.f;
    for (int i = t; i < CPG * HW / 4; i += 256) {
        float4 v = p[i];
        s += v.x + v.y + v.z + v.w;
        ss += v.x * v.x + v.y * v.y + v.z * v.z + v.w * v.w;
    }
    for (int o = 32; o; o >>= 1) { s += __shfl_down(s, o); ss += __shfl_down(ss, o); }
    __shared__ float as[4], ass[4];
    int w = t >> 6;
    if ((t & 63) == 0) { as[w] = s; ass[w] = ss; }
    __syncthreads();
    if (t < 8) {
        float S = as[0] + as[1] + as[2] + as[3];
        float SS = ass[0] + ass[1] + ass[2] + ass[3];
        float mean = S / (float)(CPG * HW);
        float var = SS / (float)(CPG * HW) - mean * mean;
        float rstd = rsqrtf(var + EPSV);
        int b = bg >> 5, g = bg & 31;
        int c = g * CPG + t;
        float a = rstd * scale[c];
        coefA[b * CH + c] = a;
        coefB[b * CH + c] = bias[c] - mean * a;
    }
}

// ---------------- QKV GEMM with fused GroupNorm-apply ----------------------------
__global__ __launch_bounds__(256) void qkv_kernel(const float* x,
        const float* coefA, const float* coefB,
        const unsigned short* wqkv_t, const float* bqkv,
        unsigned short* qb, unsigned short* kb, unsigned short* vb) {
    int t = threadIdx.x;
    int wv = t >> 6, lane = t & 63, quad = lane >> 4, ln = lane & 15;
    int wr = wv >> 1, wc = wv & 1;
    int bx = blockIdx.x;
    int m0 = bx * 128 + wr * 64;          // global m for epilogue
    int n0 = blockIdx.y * 128 + wc * 64;
    int bb = bx >> 3;                     // batch
    int p0 = (bx & 7) * 128;              // spatial base

    __shared__ __align__(16) unsigned short lds_a[128][40];  // 80B row stride

    const float* xb = x + (size_t)bb * CH * HW + p0;
    const float* cA = coefA + bb * CH;
    const float* cB = coefB + bb * CH;

    int sp = t & 127;                     // p within tile
    int sbase = (t >> 7) * 2;             // slot base (0 or 2)

    f32x4 acc[4][4] = {};
    for (int k0 = 0; k0 < CH; k0 += 32) {
        bf16x8 wpk[2];
#pragma unroll
        for (int rep = 0; rep < 2; rep++) {
            int s = sbase + rep;
            int cb = k0 + s * 8;
            union { bf16x8 v8; __hip_bfloat162 h2[4]; } u;
#pragma unroll
            for (int j = 0; j < 4; j++) {
                float v0 = fmaf(xb[(size_t)(cb + 2 * j)     * HW + sp], cA[cb + 2 * j],     cB[cb + 2 * j]);
                float v1 = fmaf(xb[(size_t)(cb + 2 * j + 1) * HW + sp], cA[cb + 2 * j + 1], cB[cb + 2 * j + 1]);
                u.h2[j] = __float22bfloat162_rn(float2{v0, v1});
            }
            wpk[rep] = u.v8;
        }
        __syncthreads();                  // previous iter's fragment reads done
#pragma unroll
        for (int rep = 0; rep < 2; rep++) {
            int s = sbase + rep;
            int phys = s ^ (sp & 3);
            *reinterpret_cast<bf16x8*>(&lds_a[sp][phys * 8]) = wpk[rep];
        }
        __syncthreads();                  // tile visible
        bf16x8 af[4], bfr[4];
#pragma unroll
        for (int i = 0; i < 4; i++) {
            int p = wr * 64 + i * 16 + ln;
            af[i] = *reinterpret_cast<const bf16x8*>(&lds_a[p][(quad ^ (p & 3)) * 8]);
        }
#pragma unroll
        for (int j = 0; j < 4; j++)
            bfr[j] = *reinterpret_cast<const bf16x8*>(
                wqkv_t + (size_t)(n0 + j * 16 + ln) * CH + k0 + quad * 8);
#pragma unroll
        for (int i = 0; i < 4; i++)
#pragma unroll
            for (int j = 0; j < 4; j++)
                acc[i][j] = __builtin_amdgcn_mfma_f32_16x16x32_bf16(af[i], bfr[j], acc[i][j], 0, 0, 0);
    }
#pragma unroll
    for (int j = 0; j < 4; j++) {
        int n = n0 + j * 16 + ln;
        float bias = bqkv[n];
        int which = n >> 8;               // uniform per 16-tile
        int dh_ = n & 255;
        int head = dh_ >> 6, d = dh_ & 63;
#pragma unroll
        for (int i = 0; i < 4; i++) {
            int mb = m0 + i * 16 + quad * 4;
            int bi = mb >> 10, p = mb & 1023;
            int bh = bi * NH + head;
            if (which < 2) {
                unsigned short* dst = (which == 0 ? qb : kb) + (size_t)bh * HW * DH;
                float sc = (which == 0) ? QSCALE : 1.0f;
#pragma unroll
                for (int r = 0; r < 4; r++)
                    dst[(size_t)(p + r) * DH + d] = f2bf((acc[i][j][r] + bias) * sc);
            } else {
                unsigned short* dst = vb + ((size_t)bh * DH + d) * HW + p;
                ushort4 pk4;
                pk4.x = f2bf(acc[i][j][0] + bias);
                pk4.y = f2bf(acc[i][j][1] + bias);
                pk4.z = f2bf(acc[i][j][2] + bias);
                pk4.w = f2bf(acc[i][j][3] + bias);
                *reinterpret_cast<ushort4*>(dst) = pk4;
            }
        }
    }
}

// ---------------- attention (split-K x2): LDS-staged K/V, 32 q/wave ---------------
// Each block: 128 q x 512 keys of one bh. Writes UNNORMALIZED partial O (bf16)
// + per-(q,head) expsum; combine_kernel merges the two K-slices.
__global__ __launch_bounds__(256) void attn_kernel(const unsigned short* qb,
        const unsigned short* kb, const unsigned short* vb,
        unsigned short* opart0, unsigned short* opart1,
        float* lsum0, float* lsum1) {
    int qblk = blockIdx.x, bh = blockIdx.y, ksl = blockIdx.z;
    int t = threadIdx.x;
    int wv = t >> 6, lane = t & 63, quad = lane >> 4, ln = lane & 15;
    int q0 = qblk * 128 + wv * 32;

    const unsigned short* Q = qb + (size_t)bh * HW * DH;
    const unsigned short* K = kb + (size_t)bh * HW * DH + (size_t)ksl * 512 * DH;
    const unsigned short* V = vb + (size_t)bh * DH * HW + ksl * 512;

    __shared__ __align__(16) unsigned short kbuf[2][4096];   // [p][swizzled 16B chunks]
    __shared__ __align__(16) unsigned short vbuf[2][4096];
    __shared__ __align__(16) unsigned short pbuf[4][2][16][72];

    // staging: chunk c -> row p = c>>3, stored slot (c&7), holding global chunk (c&7)^(p&7)
    int c_a = wv * 64 + lane;
    int c_b = 256 + wv * 64 + lane;
    int pa = c_a >> 3, ja = (c_a & 7) ^ (pa & 7);
    int pb = c_b >> 3, jb = (c_b & 7) ^ (pb & 7);
    const unsigned short* pka = K + (size_t)pa * DH + ja * 8;
    const unsigned short* pkb = K + (size_t)pb * DH + jb * 8;
    const unsigned short* pva = V + (size_t)pa * HW + ja * 8;
    const unsigned short* pvb = V + (size_t)pb * HW + jb * 8;
    int lofs_a = wv * 512, lofs_b = 2048 + wv * 512;

    // loop-invariant LDS fragment offsets (ushort units)
    int koffs[4][2];
#pragma unroll
    for (int mt = 0; mt < 4; mt++) {
        int p = mt * 16 + ln, sw = p & 7;
#pragma unroll
        for (int kk = 0; kk < 2; kk++)
            koffs[mt][kk] = p * 64 + (((kk * 4 + quad) ^ sw) * 8);
    }

    bf16x8 qf[2][2];
#pragma unroll
    for (int nq = 0; nq < 2; nq++)
#pragma unroll
        for (int kk = 0; kk < 2; kk++)
            qf[nq][kk] = *reinterpret_cast<const bf16x8*>(
                Q + (size_t)(q0 + nq * 16 + ln) * DH + kk * 32 + quad * 8);

    f32x4 ls[2] = {};
    f32x4 o[2][4] = {};

    // prologue: stage tile 0 into buffer 0
    gld_lds16(pka, &kbuf[0][lofs_a]);
    gld_lds16(pkb, &kbuf[0][lofs_b]);
    gld_lds16(pva, &vbuf[0][lofs_a]);
    gld_lds16(pvb, &vbuf[0][lofs_b]);
    pka += 64 * DH; pkb += 64 * DH; pva += 64; pvb += 64;

#define ATTN_TILE(B, DO_STAGE)                                                      \
    {                                                                               \
        __syncthreads();                                                            \
        if (DO_STAGE) {                                                             \
            gld_lds16(pka, &kbuf[B ^ 1][lofs_a]);                                   \
            gld_lds16(pkb, &kbuf[B ^ 1][lofs_b]);                                   \
            gld_lds16(pva, &vbuf[B ^ 1][lofs_a]);                                   \
            gld_lds16(pvb, &vbuf[B ^ 1][lofs_b]);                                   \
            pka += 64 * DH; pkb += 64 * DH; pva += 64; pvb += 64;                   \
        }                                                                           \
        bf16x8 kf[4][2], vf[4][2];                                                  \
        _Pragma("unroll")                                                           \
        for (int mt = 0; mt < 4; mt++) {                                            \
            _Pragma("unroll")                                                       \
            for (int kk = 0; kk < 2; kk++) {                                        \
                kf[mt][kk] = *reinterpret_cast<const bf16x8*>(&kbuf[B][koffs[mt][kk]]); \
                vf[mt][kk] = *reinterpret_cast<const bf16x8*>(&vbuf[B][koffs[mt][kk]]); \
            }                                                                       \
        }                                                                           \
        f32x4 s[2][4] = {};                                                         \
        _Pragma("unroll")                                                           \
        for (int nq = 0; nq < 2; nq++)                                              \
            _Pragma("unroll")                                                       \
            for (int mt = 0; mt < 4; mt++) {                                        \
                s[nq][mt] = __builtin_amdgcn_mfma_f32_16x16x32_bf16(kf[mt][0], qf[nq][0], s[nq][mt], 0, 0, 0); \
                s[nq][mt] = __builtin_amdgcn_mfma_f32_16x16x32_bf16(kf[mt][1], qf[nq][1], s[nq][mt], 0, 0, 0); \
            }                                                                       \
        _Pragma("unroll")                                                           \
        for (int nq = 0; nq < 2; nq++)                                              \
            _Pragma("unroll")                                                       \
            for (int mt = 0; mt < 4; mt++) {                                        \
                float e0 = __builtin_amdgcn_exp2f(s[nq][mt][0]);                    \
                float e1 = __builtin_amdgcn_exp2f(s[nq][mt][1]);                    \
                float e2 = __builtin_amdgcn_exp2f(s[nq][mt][2]);                    \
                float e3 = __builtin_amdgcn_exp2f(s[nq][mt][3]);                    \
                ls[nq][0] += e0; ls[nq][1] += e1;                                   \
                ls[nq][2] += e2; ls[nq][3] += e3;                                   \
                uint2 pk2;                                                          \
                pk2.x = __builtin_amdgcn_perm(fbits(e1), fbits(e0), 0x07060302u);   \
                pk2.y = __builtin_amdgcn_perm(fbits(e3), fbits(e2), 0x07060302u);   \
                *reinterpret_cast<uint2*>(&pbuf[wv][nq][ln][mt * 16 + quad * 4]) = pk2; \
            }                                                                       \
        _Pragma("unroll")                                                           \
        for (int nq = 0; nq < 2; nq++)                                              \
            _Pragma("unroll")                                                       \
            for (int kk = 0; kk < 2; kk++) {                                        \
                bf16x8 pf = *reinterpret_cast<const bf16x8*>(&pbuf[wv][nq][ln][kk * 32 + quad * 8]); \
                _Pragma("unroll")                                                   \
                for (int mt = 0; mt < 4; mt++)                                      \
                    o[nq][mt] = __builtin_amdgcn_mfma_f32_16x16x32_bf16(vf[mt][kk], pf, o[nq][mt], 0, 0, 0); \
            }                                                                       \
    }

    for (int u = 0; u < 4; u++) {
        ATTN_TILE(0, true)            // compute tile 2u,   stage tile 2u+1
        ATTN_TILE(1, (u < 3))         // compute tile 2u+1, stage tile 2u+2
    }
#undef ATTN_TILE

    unsigned short* opart = ksl ? opart1 : opart0;
    float* lsum = ksl ? lsum1 : lsum0;
    int b_ = bh >> 2, head = bh & 3;
#pragma unroll
    for (int nq = 0; nq < 2; nq++) {
        float lv = ls[nq][0] + ls[nq][1] + ls[nq][2] + ls[nq][3];
        lv += __shfl_xor(lv, 16);
        lv += __shfl_xor(lv, 32);
        int q = q0 + nq * 16 + ln;
        if (lane < 16)
            lsum[((b_ * HW + q) << 2) + head] = lv;
        unsigned short* dst = opart + ((size_t)(b_ * HW + q)) * CH + head * DH;
#pragma unroll
        for (int mt = 0; mt < 4; mt++) {
            ushort4 pk4;
            pk4.x = f2bf(o[nq][mt][0]);
            pk4.y = f2bf(o[nq][mt][1]);
            pk4.z = f2bf(o[nq][mt][2]);
            pk4.w = f2bf(o[nq][mt][3]);
            *reinterpret_cast<ushort4*>(dst + mt * 16 + quad * 4) = pk4;
        }
    }
}

// ---------------- combine: h = (O1 + O2) / (l1 + l2) -----------------------------
__global__ __launch_bounds__(256) void combine_kernel(const unsigned short* o1,
        const unsigned short* o2, const float* l1, const float* l2,
        unsigned short* h_t) {
    int tid = blockIdx.x * 256 + threadIdx.x;
    int base = tid * 8;                                  // 8 bf16 per thread
    int lidx = ((base >> 8) << 2) + ((base >> 6) & 3);   // (b*HW+q)*4 + head
    float inv = 1.0f / (l1[lidx] + l2[lidx]);
    uint4 a = *reinterpret_cast<const uint4*>(o1 + base);
    uint4 b = *reinterpret_cast<const uint4*>(o2 + base);
    unsigned int av[4] = {a.x, a.y, a.z, a.w};
    unsigned int bv4[4] = {b.x, b.y, b.z, b.w};
    unsigned int rv[4];
#pragma unroll
    for (int i = 0; i < 4; i++) {
        float g0 = (bfu(av[i] << 16) + bfu(bv4[i] << 16)) * inv;
        float g1 = (bfu(av[i] & 0xffff0000u) + bfu(bv4[i] & 0xffff0000u)) * inv;
        union { __hip_bfloat162 h2; unsigned int u; } cv;
        cv.h2 = __float22bfloat162_rn(float2{g0, g1});
        rv[i] = cv.u;
    }
    *reinterpret_cast<uint4*>(h_t + base) = make_uint4(rv[0], rv[1], rv[2], rv[3]);
}

// ---------------- proj GEMM + bias + residual + /sqrt(2) -------------------------
// 16x256 block tile (1024 blocks -> 4 blocks/CU), one 64-n slab per wave.
__global__ __launch_bounds__(256) void proj_kernel(const unsigned short* h_t,
        const unsigned short* wp_t, const float* bp, const float* x, float* out) {
    int t = threadIdx.x;
    int wv = t >> 6, lane = t & 63, quad = lane >> 4, ln = lane & 15;
    int m0 = blockIdx.x * 16;
    int n0 = wv * 64;

    f32x4 acc[4] = {};
    for (int k0 = 0; k0 < CH; k0 += 32) {
        int koff = k0 + quad * 8;
        bf16x8 af = *reinterpret_cast<const bf16x8*>(h_t + (size_t)(m0 + ln) * CH + koff);
        bf16x8 bfr[4];
#pragma unroll
        for (int j = 0; j < 4; j++)
            bfr[j] = *reinterpret_cast<const bf16x8*>(wp_t + (size_t)(n0 + j * 16 + ln) * CH + koff);
#pragma unroll
        for (int j = 0; j < 4; j++)
            acc[j] = __builtin_amdgcn_mfma_f32_16x16x32_bf16(af, bfr[j], acc[j], 0, 0, 0);
    }
    const float inv_s2 = 0.70710678118654752440f;
    int mb = m0 + quad * 4;
    int bi = mb >> 10, p = mb & 1023;
#pragma unroll
    for (int j = 0; j < 4; j++) {
        int n = n0 + j * 16 + ln;
        float bias = bp[n];
        size_t off = ((size_t)(bi * CH + n)) * HW + p;
        float4 xv = *reinterpret_cast<const float4*>(x + off);
        float4 ov;
        ov.x = (xv.x + acc[j][0] + bias) * inv_s2;
        ov.y = (xv.y + acc[j][1] + bias) * inv_s2;
        ov.z = (xv.z + acc[j][2] + bias) * inv_s2;
        ov.w = (xv.w + acc[j][3] + bias) * inv_s2;
        *reinterpret_cast<float4*>(out + off) = ov;
    }
}

extern "C" void kernel_launch(void* const* d_in, const int* in_sizes, int n_in,
                              void* d_out, int out_size, void* d_ws, size_t ws_size,
                              hipStream_t stream) {
    const float* x        = (const float*)d_in[0];
    const float* gn_scale = (const float*)d_in[1];
    const float* gn_bias  = (const float*)d_in[2];
    const float* Wq = (const float*)d_in[3];
    const float* bq = (const float*)d_in[4];
    const float* Wk = (const float*)d_in[5];
    const float* bk = (const float*)d_in[6];
    const float* Wv = (const float*)d_in[7];
    const float* bv = (const float*)d_in[8];
    const float* Wp = (const float*)d_in[9];
    const float* bp = (const float*)d_in[10];
    float* out = (float*)d_out;

    char* ws = (char*)d_ws;
    // ws layout (bytes), total ~52 MB
    float*          bqkv   = (float*)(ws + 0);
    float*          coefA  = (float*)(ws + 4096);
    float*          coefB  = (float*)(ws + 20480);
    unsigned short* wqkv_t = (unsigned short*)(ws + 36864);    // 384 KB
    unsigned short* wp_t   = (unsigned short*)(ws + 430080);   // 128 KB
    unsigned short* h_t    = (unsigned short*)(ws + 1048576);  // 8.39 MB
    unsigned short* qb     = (unsigned short*)(ws + 9437184);
    unsigned short* kb     = (unsigned short*)(ws + 17825792);
    unsigned short* vb     = (unsigned short*)(ws + 26214400);
    unsigned short* opart0 = (unsigned short*)(ws + 34603008);
    unsigned short* opart1 = (unsigned short*)(ws + 42991616);
    float*          lsum0  = (float*)(ws + 51380224);
    float*          lsum1  = (float*)(ws + 51642368);

    prep_stats_kernel<<<1536, 256, 0, stream>>>(x, gn_scale, gn_bias, Wq, Wk, Wv, Wp,
                                                bq, bk, bv, coefA, coefB, wqkv_t, wp_t, bqkv);
    qkv_kernel<<<dim3(128, 6), 256, 0, stream>>>(x, coefA, coefB, wqkv_t, bqkv, qb, kb, vb);
    attn_kernel<<<dim3(8, 64, 2), 256, 0, stream>>>(qb, kb, vb, opart0, opart1, lsum0, lsum1);
    combine_kernel<<<4096, 256, 0, stream>>>(opart0, opart1, lsum0, lsum1, h_t);
    proj_kernel<<<dim3(1024, 1), 256, 0, stream>>>(h_t, wp_t, bp, x, out);
}

// Round 7
// 162.697 us; speedup vs baseline: 1.0939x; 1.0939x over previous
//
#include <hip/hip_runtime.h>
#include <hip/hip_bf16.h>

#define BATCH 16
#define CH    256
#define HW    1024
#define NH    4
#define DH    64
#define NG    32
#define CPG   8
#define EPSV  1e-6f

// log2(e) / sqrt(C) folded into Q so softmax = exp2(S_scaled)
#define QSCALE 0.090168440055558706f

typedef __bf16 bf16x8 __attribute__((ext_vector_type(8)));
typedef float  f32x4  __attribute__((ext_vector_type(4)));

__device__ __forceinline__ unsigned short f2bf(float f) {
    union { __hip_bfloat16 h; unsigned short u; } cv;
    cv.h = __float2bfloat16(f);
    return cv.u;
}

__device__ __forceinline__ unsigned int fbits(float f) {
    union { float f; unsigned int u; } cv; cv.f = f; return cv.u;
}

__device__ __forceinline__ void gld_lds16(const unsigned short* g, unsigned short* l) {
    __builtin_amdgcn_global_load_lds(
        (const __attribute__((address_space(1))) void*)g,
        (__attribute__((address_space(3))) void*)l, 16, 0, 0);
}

// ---------------- merged: GN stats (blocks 0..511) + weight prep (blocks 512+) ----
__global__ void prep_stats_kernel(const float* x, const float* scale, const float* bias,
                                  const float* Wq, const float* Wk, const float* Wv,
                                  const float* Wp, const float* bq, const float* bk,
                                  const float* bv, float* coefA, float* coefB,
                                  unsigned short* wqkv_t, unsigned short* wp_t,
                                  float* bqkv) {
    int t = threadIdx.x;
    if (blockIdx.x >= 512) {
        int idx = (blockIdx.x - 512) * 256 + t;
        if (idx < 768 * 256) {
            int n = idx >> 8, c = idx & 255;
            const float* W = (n < 256) ? Wq : (n < 512) ? Wk : Wv;
            int d = n & 255;
            wqkv_t[idx] = f2bf(W[c * 256 + d]);
        } else if (idx < 768 * 256 + 256 * 256) {
            int j = idx - 768 * 256;
            int n = j >> 8, c = j & 255;
            wp_t[j] = f2bf(Wp[c * 256 + n]);
        }
        if (idx < 768)
            bqkv[idx] = (idx < 256) ? bq[idx] : (idx < 512) ? bk[idx - 256] : bv[idx - 512];
        return;
    }
    int bg = blockIdx.x;                       // b*32+g, group data contiguous
    const float4* p = reinterpret_cast<const float4*>(x + (size_t)bg * (CPG * HW));
    float s = 0.f, ss = 0.f;
    for (int i = t; i < CPG * HW / 4; i += 256) {
        float4 v = p[i];
        s += v.x + v.y + v.z + v.w;
        ss += v.x * v.x + v.y * v.y + v.z * v.z + v.w * v.w;
    }
    for (int o = 32; o; o >>= 1) { s += __shfl_down(s, o); ss += __shfl_down(ss, o); }
    __shared__ float as[4], ass[4];
    int w = t >> 6;
    if ((t & 63) == 0) { as[w] = s; ass[w] = ss; }
    __syncthreads();
    if (t < 8) {
        float S = as[0] + as[1] + as[2] + as[3];
        float SS = ass[0] + ass[1] + ass[2] + ass[3];
        float mean = S / (float)(CPG * HW);
        float var = SS / (float)(CPG * HW) - mean * mean;
        float rstd = rsqrtf(var + EPSV);
        int b = bg >> 5, g = bg & 31;
        int c = g * CPG + t;
        float a = rstd * scale[c];
        coefA[b * CH + c] = a;
        coefB[b * CH + c] = bias[c] - mean * a;
    }
}

// ---------------- QKV GEMM with fused GroupNorm-apply ----------------------------
// A-tile built in LDS from x (fmaf normalize + RNE bf16 pack). Epilogue for Q/K
// bounces acc through a per-wave LDS f32 tile so the contiguous 64p x 64d output
// slab is stored with 8 dwordx4 (8 segments each) instead of 64 scalar stores.
__global__ __launch_bounds__(256) void qkv_kernel(const float* x,
        const float* coefA, const float* coefB,
        const unsigned short* wqkv_t, const float* bqkv,
        unsigned short* qb, unsigned short* kb, unsigned short* vb) {
    int t = threadIdx.x;
    int wv = t >> 6, lane = t & 63, quad = lane >> 4, ln = lane & 15;
    int wr = wv >> 1, wc = wv & 1;
    int bx = blockIdx.x;
    int m0 = bx * 128 + wr * 64;          // global m for epilogue (64-aligned)
    int n0 = blockIdx.y * 128 + wc * 64;  // 64-aligned -> one head per wave
    int bb = bx >> 3;                     // batch
    int p0 = (bx & 7) * 128;              // spatial base of the A-tile

    __shared__ __align__(16) unsigned short lds_a[128][40];  // 80B row stride
    __shared__ __align__(16) float ebuf[4][16][68];          // per-wave epilogue tile

    const float* xb = x + (size_t)bb * CH * HW + p0;
    const float* cA = coefA + bb * CH;
    const float* cB = coefB + bb * CH;

    int sp = t & 127;                     // p within tile
    int sbase = (t >> 7) * 2;             // slot base (0 or 2)

    f32x4 acc[4][4] = {};
    for (int k0 = 0; k0 < CH; k0 += 32) {
        bf16x8 wpk[2];
#pragma unroll
        for (int rep = 0; rep < 2; rep++) {
            int s = sbase + rep;
            int cb = k0 + s * 8;
            union { bf16x8 v8; __hip_bfloat162 h2[4]; } u;
#pragma unroll
            for (int j = 0; j < 4; j++) {
                float v0 = fmaf(xb[(size_t)(cb + 2 * j)     * HW + sp], cA[cb + 2 * j],     cB[cb + 2 * j]);
                float v1 = fmaf(xb[(size_t)(cb + 2 * j + 1) * HW + sp], cA[cb + 2 * j + 1], cB[cb + 2 * j + 1]);
                u.h2[j] = __float22bfloat162_rn(float2{v0, v1});
            }
            wpk[rep] = u.v8;
        }
        __syncthreads();                  // previous iter's fragment reads done
#pragma unroll
        for (int rep = 0; rep < 2; rep++) {
            int s = sbase + rep;
            int phys = s ^ (sp & 3);
            *reinterpret_cast<bf16x8*>(&lds_a[sp][phys * 8]) = wpk[rep];
        }
        __syncthreads();                  // tile visible
        bf16x8 af[4], bfr[4];
#pragma unroll
        for (int i = 0; i < 4; i++) {
            int p = wr * 64 + i * 16 + ln;
            af[i] = *reinterpret_cast<const bf16x8*>(&lds_a[p][(quad ^ (p & 3)) * 8]);
        }
#pragma unroll
        for (int j = 0; j < 4; j++)
            bfr[j] = *reinterpret_cast<const bf16x8*>(
                wqkv_t + (size_t)(n0 + j * 16 + ln) * CH + k0 + quad * 8);
#pragma unroll
        for (int i = 0; i < 4; i++)
#pragma unroll
            for (int j = 0; j < 4; j++)
                acc[i][j] = __builtin_amdgcn_mfma_f32_16x16x32_bf16(af[i], bfr[j], acc[i][j], 0, 0, 0);
    }

    int whichw = n0 >> 8;                 // 0=Q 1=K 2=V, uniform per wave
    int headw = (n0 >> 6) & 3;
    int bi = m0 >> 10;                    // batch (m-range within one batch)
    int p0w = m0 & 1023;
    int bh = bi * NH + headw;
    float biasj[4];
#pragma unroll
    for (int j = 0; j < 4; j++) biasj[j] = bqkv[n0 + j * 16 + ln];

    if (whichw < 2) {
        // ---- Q/K: LDS-transpose epilogue, coalesced dwordx4 stores ----
        unsigned short* dst = (whichw == 0 ? qb : kb) + (size_t)bh * HW * DH;
        float sc = (whichw == 0) ? QSCALE : 1.0f;
#pragma unroll
        for (int i = 0; i < 4; i++) {
#pragma unroll
            for (int j = 0; j < 4; j++)
#pragma unroll
                for (int r = 0; r < 4; r++)
                    ebuf[wv][quad * 4 + r][j * 16 + ln] = (acc[i][j][r] + biasj[j]) * sc;
            // per-wave region: in-order DS ops, no barrier needed
#pragma unroll
            for (int pg = 0; pg < 2; pg++) {
                int mloc = pg * 8 + quad * 2 + (ln >> 3);
                int dd = (ln & 7) * 8;
                f32x4 a0 = *reinterpret_cast<const f32x4*>(&ebuf[wv][mloc][dd]);
                f32x4 a1 = *reinterpret_cast<const f32x4*>(&ebuf[wv][mloc][dd + 4]);
                union { uint4 u4; unsigned int u[4]; } o;
                union { __hip_bfloat162 h2; unsigned int u; } cv;
                cv.h2 = __float22bfloat162_rn(float2{a0[0], a0[1]}); o.u[0] = cv.u;
                cv.h2 = __float22bfloat162_rn(float2{a0[2], a0[3]}); o.u[1] = cv.u;
                cv.h2 = __float22bfloat162_rn(float2{a1[0], a1[1]}); o.u[2] = cv.u;
                cv.h2 = __float22bfloat162_rn(float2{a1[2], a1[3]}); o.u[3] = cv.u;
                *reinterpret_cast<uint4*>(dst + (size_t)(p0w + i * 16 + mloc) * DH + dd) = o.u4;
            }
        }
    } else {
        // ---- V: transposed layout [bh][d][p], ushort4 stores (as before) ----
        unsigned short* dstv = vb + (size_t)bh * DH * HW;
#pragma unroll
        for (int j = 0; j < 4; j++) {
            int d = j * 16 + ln;
#pragma unroll
            for (int i = 0; i < 4; i++) {
                int p = p0w + i * 16 + quad * 4;
                ushort4 pk4;
                pk4.x = f2bf(acc[i][j][0] + biasj[j]);
                pk4.y = f2bf(acc[i][j][1] + biasj[j]);
                pk4.z = f2bf(acc[i][j][2] + biasj[j]);
                pk4.w = f2bf(acc[i][j][3] + biasj[j]);
                *reinterpret_cast<ushort4*>(dstv + (size_t)d * HW + p) = pk4;
            }
        }
    }
}

// ---------------- attention: LDS-staged K/V, 32 q/wave, XCD-local swizzle ---------
// Grid 512 linear; bh = linear & 63 so all 8 q-blocks of one bh land on the same
// XCD (linear%8 == bh%8): per-XCD K/V footprint = 8 bh * 512 KB = 4 MB = L2.
__global__ __launch_bounds__(256) void attn_kernel(const unsigned short* qb,
        const unsigned short* kb, const unsigned short* vb, unsigned short* h_t) {
    int linear = blockIdx.x;
    int bh = linear & 63;
    int qblk = linear >> 6;
    int t = threadIdx.x;
    int wv = t >> 6, lane = t & 63, quad = lane >> 4, ln = lane & 15;
    int q0 = qblk * 128 + wv * 32;

    const unsigned short* Q = qb + (size_t)bh * HW * DH;
    const unsigned short* K = kb + (size_t)bh * HW * DH;
    const unsigned short* V = vb + (size_t)bh * DH * HW;

    __shared__ __align__(16) unsigned short kbuf[2][4096];   // [p][swizzled 16B chunks]
    __shared__ __align__(16) unsigned short vbuf[2][4096];
    __shared__ __align__(16) unsigned short pbuf[4][2][16][72];

    // staging: chunk c -> row p = c>>3, stored slot (c&7), holding global chunk (c&7)^(p&7)
    int c_a = wv * 64 + lane;
    int c_b = 256 + wv * 64 + lane;
    int pa = c_a >> 3, ja = (c_a & 7) ^ (pa & 7);
    int pb = c_b >> 3, jb = (c_b & 7) ^ (pb & 7);
    const unsigned short* pka = K + (size_t)pa * DH + ja * 8;
    const unsigned short* pkb = K + (size_t)pb * DH + jb * 8;
    const unsigned short* pva = V + (size_t)pa * HW + ja * 8;
    const unsigned short* pvb = V + (size_t)pb * HW + jb * 8;
    int lofs_a = wv * 512, lofs_b = 2048 + wv * 512;

    // loop-invariant LDS fragment offsets (ushort units)
    int koffs[4][2];
#pragma unroll
    for (int mt = 0; mt < 4; mt++) {
        int p = mt * 16 + ln, sw = p & 7;
#pragma unroll
        for (int kk = 0; kk < 2; kk++)
            koffs[mt][kk] = p * 64 + (((kk * 4 + quad) ^ sw) * 8);
    }

    bf16x8 qf[2][2];
#pragma unroll
    for (int nq = 0; nq < 2; nq++)
#pragma unroll
        for (int kk = 0; kk < 2; kk++)
            qf[nq][kk] = *reinterpret_cast<const bf16x8*>(
                Q + (size_t)(q0 + nq * 16 + ln) * DH + kk * 32 + quad * 8);

    f32x4 ls[2] = {};
    f32x4 o[2][4] = {};

    // prologue: stage tile 0 into buffer 0
    gld_lds16(pka, &kbuf[0][lofs_a]);
    gld_lds16(pkb, &kbuf[0][lofs_b]);
    gld_lds16(pva, &vbuf[0][lofs_a]);
    gld_lds16(pvb, &vbuf[0][lofs_b]);
    pka += 64 * DH; pkb += 64 * DH; pva += 64; pvb += 64;

#define ATTN_TILE(B, DO_STAGE)                                                      \
    {                                                                               \
        __syncthreads();                                                            \
        if (DO_STAGE) {                                                             \
            gld_lds16(pka, &kbuf[B ^ 1][lofs_a]);                                   \
            gld_lds16(pkb, &kbuf[B ^ 1][lofs_b]);                                   \
            gld_lds16(pva, &vbuf[B ^ 1][lofs_a]);                                   \
            gld_lds16(pvb, &vbuf[B ^ 1][lofs_b]);                                   \
            pka += 64 * DH; pkb += 64 * DH; pva += 64; pvb += 64;                   \
        }                                                                           \
        bf16x8 kf[4][2], vf[4][2];                                                  \
        _Pragma("unroll")                                                           \
        for (int mt = 0; mt < 4; mt++) {                                            \
            _Pragma("unroll")                                                       \
            for (int kk = 0; kk < 2; kk++) {                                        \
                kf[mt][kk] = *reinterpret_cast<const bf16x8*>(&kbuf[B][koffs[mt][kk]]); \
                vf[mt][kk] = *reinterpret_cast<const bf16x8*>(&vbuf[B][koffs[mt][kk]]); \
            }                                                                       \
        }                                                                           \
        f32x4 s[2][4] = {};                                                         \
        _Pragma("unroll")                                                           \
        for (int nq = 0; nq < 2; nq++)                                              \
            _Pragma("unroll")                                                       \
            for (int mt = 0; mt < 4; mt++) {                                        \
                s[nq][mt] = __builtin_amdgcn_mfma_f32_16x16x32_bf16(kf[mt][0], qf[nq][0], s[nq][mt], 0, 0, 0); \
                s[nq][mt] = __builtin_amdgcn_mfma_f32_16x16x32_bf16(kf[mt][1], qf[nq][1], s[nq][mt], 0, 0, 0); \
            }                                                                       \
        _Pragma("unroll")                                                           \
        for (int nq = 0; nq < 2; nq++)                                              \
            _Pragma("unroll")                                                       \
            for (int mt = 0; mt < 4; mt++) {                                        \
                float e0 = __builtin_amdgcn_exp2f(s[nq][mt][0]);                    \
                float e1 = __builtin_amdgcn_exp2f(s[nq][mt][1]);                    \
                float e2 = __builtin_amdgcn_exp2f(s[nq][mt][2]);                    \
                float e3 = __builtin_amdgcn_exp2f(s[nq][mt][3]);                    \
                ls[nq][0] += e0; ls[nq][1] += e1;                                   \
                ls[nq][2] += e2; ls[nq][3] += e3;                                   \
                uint2 pk2;                                                          \
                pk2.x = __builtin_amdgcn_perm(fbits(e1), fbits(e0), 0x07060302u);   \
                pk2.y = __builtin_amdgcn_perm(fbits(e3), fbits(e2), 0x07060302u);   \
                *reinterpret_cast<uint2*>(&pbuf[wv][nq][ln][mt * 16 + quad * 4]) = pk2; \
            }                                                                       \
        _Pragma("unroll")                                                           \
        for (int nq = 0; nq < 2; nq++)                                              \
            _Pragma("unroll")                                                       \
            for (int kk = 0; kk < 2; kk++) {                                        \
                bf16x8 pf = *reinterpret_cast<const bf16x8*>(&pbuf[wv][nq][ln][kk * 32 + quad * 8]); \
                _Pragma("unroll")                                                   \
                for (int mt = 0; mt < 4; mt++)                                      \
                    o[nq][mt] = __builtin_amdgcn_mfma_f32_16x16x32_bf16(vf[mt][kk], pf, o[nq][mt], 0, 0, 0); \
            }                                                                       \
    }

    for (int u = 0; u < 8; u++) {
        ATTN_TILE(0, true)            // compute tile 2u,   stage tile 2u+1
        ATTN_TILE(1, (u < 7))         // compute tile 2u+1, stage tile 2u+2
    }
#undef ATTN_TILE

    int b_ = bh >> 2, head = bh & 3;
#pragma unroll
    for (int nq = 0; nq < 2; nq++) {
        float lsum = ls[nq][0] + ls[nq][1] + ls[nq][2] + ls[nq][3];
        lsum += __shfl_xor(lsum, 16);
        lsum += __shfl_xor(lsum, 32);
        float inv = 1.0f / lsum;
        unsigned short* dst = h_t + ((size_t)b_ * HW + q0 + nq * 16 + ln) * CH + head * DH;
#pragma unroll
        for (int mt = 0; mt < 4; mt++) {
            ushort4 pk4;
            pk4.x = f2bf(o[nq][mt][0] * inv);
            pk4.y = f2bf(o[nq][mt][1] * inv);
            pk4.z = f2bf(o[nq][mt][2] * inv);
            pk4.w = f2bf(o[nq][mt][3] * inv);
            *reinterpret_cast<ushort4*>(dst + mt * 16 + quad * 4) = pk4;
        }
    }
}

// ---------------- proj GEMM + bias + residual + /sqrt(2) -------------------------
// 16x256 block tile (1024 blocks -> 4 blocks/CU), one 64-n slab per wave.
__global__ __launch_bounds__(256) void proj_kernel(const unsigned short* h_t,
        const unsigned short* wp_t, const float* bp, const float* x, float* out) {
    int t = threadIdx.x;
    int wv = t >> 6, lane = t & 63, quad = lane >> 4, ln = lane & 15;
    int m0 = blockIdx.x * 16;
    int n0 = wv * 64;

    f32x4 acc[4] = {};
    for (int k0 = 0; k0 < CH; k0 += 32) {
        int koff = k0 + quad * 8;
        bf16x8 af = *reinterpret_cast<const bf16x8*>(h_t + (size_t)(m0 + ln) * CH + koff);
        bf16x8 bfr[4];
#pragma unroll
        for (int j = 0; j < 4; j++)
            bfr[j] = *reinterpret_cast<const bf16x8*>(wp_t + (size_t)(n0 + j * 16 + ln) * CH + koff);
#pragma unroll
        for (int j = 0; j < 4; j++)
            acc[j] = __builtin_amdgcn_mfma_f32_16x16x32_bf16(af, bfr[j], acc[j], 0, 0, 0);
    }
    const float inv_s2 = 0.70710678118654752440f;
    int mb = m0 + quad * 4;
    int bi = mb >> 10, p = mb & 1023;
#pragma unroll
    for (int j = 0; j < 4; j++) {
        int n = n0 + j * 16 + ln;
        float bias = bp[n];
        size_t off = ((size_t)(bi * CH + n)) * HW + p;
        float4 xv = *reinterpret_cast<const float4*>(x + off);
        float4 ov;
        ov.x = (xv.x + acc[j][0] + bias) * inv_s2;
        ov.y = (xv.y + acc[j][1] + bias) * inv_s2;
        ov.z = (xv.z + acc[j][2] + bias) * inv_s2;
        ov.w = (xv.w + acc[j][3] + bias) * inv_s2;
        *reinterpret_cast<float4*>(out + off) = ov;
    }
}

extern "C" void kernel_launch(void* const* d_in, const int* in_sizes, int n_in,
                              void* d_out, int out_size, void* d_ws, size_t ws_size,
                              hipStream_t stream) {
    const float* x        = (const float*)d_in[0];
    const float* gn_scale = (const float*)d_in[1];
    const float* gn_bias  = (const float*)d_in[2];
    const float* Wq = (const float*)d_in[3];
    const float* bq = (const float*)d_in[4];
    const float* Wk = (const float*)d_in[5];
    const float* bk = (const float*)d_in[6];
    const float* Wv = (const float*)d_in[7];
    const float* bv = (const float*)d_in[8];
    const float* Wp = (const float*)d_in[9];
    const float* bp = (const float*)d_in[10];
    float* out = (float*)d_out;

    char* ws = (char*)d_ws;
    // ws layout (bytes), total ~34.6 MB
    float*          bqkv   = (float*)(ws + 0);
    float*          coefA  = (float*)(ws + 4096);
    float*          coefB  = (float*)(ws + 20480);
    unsigned short* wqkv_t = (unsigned short*)(ws + 36864);    // 384 KB
    unsigned short* wp_t   = (unsigned short*)(ws + 430080);   // 128 KB
    unsigned short* h_t    = (unsigned short*)(ws + 1048576);  // 8.39 MB
    unsigned short* qb     = (unsigned short*)(ws + 9437184);
    unsigned short* kb     = (unsigned short*)(ws + 17825792);
    unsigned short* vb     = (unsigned short*)(ws + 26214400);

    prep_stats_kernel<<<1536, 256, 0, stream>>>(x, gn_scale, gn_bias, Wq, Wk, Wv, Wp,
                                                bq, bk, bv, coefA, coefB, wqkv_t, wp_t, bqkv);
    qkv_kernel<<<dim3(128, 6), 256, 0, stream>>>(x, coefA, coefB, wqkv_t, bqkv, qb, kb, vb);
    attn_kernel<<<512, 256, 0, stream>>>(qb, kb, vb, h_t);
    proj_kernel<<<dim3(1024, 1), 256, 0, stream>>>(h_t, wp_t, bp, x, out);
}